// Round 16
// baseline (136.833 us; speedup 1.0000x reference)
//
#include <hip/hip_runtime.h>
#include <math.h>

#define EPS_F 1.1754943508222875e-38f

typedef __attribute__((ext_vector_type(8))) _Float16 half8;
typedef __attribute__((ext_vector_type(4))) float f32x4;
typedef __attribute__((ext_vector_type(8))) unsigned short ushort8;

__device__ __forceinline__ unsigned short f2h(float f) {
  _Float16 h = (_Float16)f;
  return __builtin_bit_cast(unsigned short, h);
}
__device__ __forceinline__ float h2f(unsigned short u) {
  return (float)__builtin_bit_cast(_Float16, u);
}

// async global->LDS, 16B/lane; LDS dest = wave-uniform base (+ lane*16 by HW)
__device__ __forceinline__ void gload16(const void* g, void* l) {
  __builtin_amdgcn_global_load_lds(
      (const __attribute__((address_space(1))) void*)g,
      (__attribute__((address_space(3))) void*)l, 16, 0, 0);
}

// ---------------- prep: x transpose + f16 convert ----------------
__global__ __launch_bounds__(256) void k_prep_x(const float* __restrict__ in,
                                                unsigned short* __restrict__ x) {
  __shared__ float t[32][33];
  int c0 = blockIdx.x * 32, p0 = blockIdx.y * 32, b = blockIdx.z;
  int tx = threadIdx.x & 31, ty = threadIdx.x >> 5;
#pragma unroll
  for (int i = ty; i < 32; i += 8)
    t[i][tx] = in[(b * 256 + p0 + i) * 512 + c0 + tx];
  __syncthreads();
#pragma unroll
  for (int i = ty; i < 32; i += 8)
    x[(b * 512 + c0 + i) * 256 + p0 + tx] = f2h(t[tx][i]);
}

// ======== fused prep: bid<4096 -> prep_w; else -> transposes (wvT / woT) ========
__global__ __launch_bounds__(256) void k_prepwt(
    const float* __restrict__ Wq, const float* __restrict__ Wk,
    const float* __restrict__ Wv, const float* __restrict__ Wo,
    const float* __restrict__ bq, const float* __restrict__ bk,
    const float* __restrict__ sigma,
    unsigned short* __restrict__ wd, unsigned short* __restrict__ woh,
    unsigned short* __restrict__ wqh, float* __restrict__ bdr,
    float* __restrict__ pbk, unsigned short* __restrict__ wvT,
    unsigned short* __restrict__ woT, float* __restrict__ pbv) {
  __shared__ float t[32][33];
  __shared__ float r1[4];
  const int bid = blockIdx.x;
  const int lane = threadIdx.x & 63, w = threadIdx.x >> 6;
  if (bid < 4096) {
    int gid = bid * 256 + threadIdx.x;
    int i4 = gid * 4;
    int rm = i4 >> 8, p = i4 & 255, m = rm & 255;
    const float4 wk = *(const float4*)(Wk + i4);
    const float4 wq = *(const float4*)(Wq + m * 256 + p);
    float rs = 1.0f / (sigma[rm] + EPS_F);
    ushort4 d;
    d.x = f2h((wq.x - wk.x) * rs); d.y = f2h((wq.y - wk.y) * rs);
    d.z = f2h((wq.z - wk.z) * rs); d.w = f2h((wq.w - wk.w) * rs);
    *(ushort4*)(wd + i4) = d;
    float ak = fabsf(wk.x) + fabsf(wk.y) + fabsf(wk.z) + fabsf(wk.w);
    if (p == 0) bdr[rm] = (bq[m] - bk[rm]) * rs;
    if (gid < 65536) {
      woh[gid] = f2h(Wo[gid]);
      ushort4 q4;
      q4.x = f2h(wq.x); q4.y = f2h(wq.y); q4.z = f2h(wq.z); q4.w = f2h(wq.w);
      *(ushort4*)(wqh + i4) = q4;
    }
#pragma unroll
    for (int dlt = 1; dlt < 64; dlt <<= 1) ak += __shfl_xor(ak, dlt);
    if (lane == 0) r1[w] = ak;
    __syncthreads();
    if (threadIdx.x == 0)
      pbk[bid] = r1[0] + r1[1] + r1[2] + r1[3];
  } else {
    int tt = bid - 4096;
    int z = tt >> 6, rem = tt & 63;
    int bx = rem & 7, by = rem >> 3;
    int tx = threadIdx.x & 31, ty = threadIdx.x >> 5;
    if (z < 64) {
      int p0 = bx * 32, m0 = by * 32, r = z;
      float av = 0.f;
#pragma unroll
      for (int i = ty; i < 32; i += 8) {
        float v = Wv[(size_t)(r * 256 + m0 + i) * 256 + p0 + tx];
        t[i][tx] = v;
        av += fabsf(v);
      }
      __syncthreads();
#pragma unroll
      for (int i = ty; i < 32; i += 8)
        wvT[(size_t)r * 65536 + (p0 + i) * 256 + m0 + tx] = f2h(t[tx][i]);
#pragma unroll
      for (int d = 1; d < 64; d <<= 1) av += __shfl_xor(av, d);
      if (lane == 0) r1[w] = av;
      __syncthreads();
      if (threadIdx.x == 0)
        pbv[r * 64 + by * 8 + bx] = r1[0] + r1[1] + r1[2] + r1[3];
    } else {
      int p0 = bx * 32, m0 = by * 32;
#pragma unroll
      for (int i = ty; i < 32; i += 8)
        t[i][tx] = Wo[(p0 + i) * 256 + m0 + tx];
      __syncthreads();
#pragma unroll
      for (int i = ty; i < 32; i += 8)
        woT[(m0 + i) * 256 + p0 + tx] = f2h(t[tx][i]);
    }
  }
}

// ======== fused weight-GEMMs: bid<256 -> gw; 256..259 -> wqwo; 260..323 -> hv ========
__global__ __launch_bounds__(256) void k_gwx(
    const unsigned short* __restrict__ woh, const unsigned short* __restrict__ wvT,
    const unsigned short* __restrict__ wqh, const unsigned short* __restrict__ woT,
    const float* __restrict__ bv,
    unsigned short* __restrict__ G, float* __restrict__ pbw,
    float* __restrict__ hv) {
  __shared__ unsigned short As[128 * 64];
  __shared__ unsigned short Bs[128 * 64];
  __shared__ float red4[4];
  __shared__ float bvl[256];
  const int bid = blockIdx.x;
  const int tid = threadIdx.x, w = tid >> 6, lane = tid & 63;
  const int wr = w >> 1, wc = w & 1, cl = lane & 15, kg = lane >> 4;

  if (bid < 260) {
    const bool isgw = bid < 256;
    const int r = bid >> 2;
    const int rowbase = isgw ? (((bid >> 1) & 1) * 128) : (((bid - 256) >> 1) * 128);
    const int colbase = isgw ? ((bid & 1) * 128) : (((bid - 256) & 1) * 128);
    const unsigned short* Aglob = isgw ? woh : wqh;
    const unsigned short* Bglob = isgw ? (wvT + (size_t)r * 65536) : woT;

    f32x4 acc[4][4];
#pragma unroll
    for (int i = 0; i < 4; ++i)
#pragma unroll
      for (int j = 0; j < 4; ++j) acc[i][j] = (f32x4){0.f, 0.f, 0.f, 0.f};

    for (int tks = 0; tks < 4; ++tks) {
      const int kc = tks * 64;
      __syncthreads();
#pragma unroll
      for (int j = 0; j < 4; ++j) {
        int s = w * 4 + j;
        int ch = s * 64 + lane;
        int row = ch >> 3, c = ch & 7;
        gload16(Aglob + (rowbase + row) * 256 + kc + ((c ^ (row & 7)) << 3),
                As + s * 512);
        gload16(Bglob + (colbase + row) * 256 + kc + ((c ^ (row & 7)) << 3),
                Bs + s * 512);
      }
      __syncthreads();
#pragma unroll
      for (int kk = 0; kk < 2; ++kk) {
        half8 a[4], b[4];
        int g = kk * 4 + kg;
#pragma unroll
        for (int i = 0; i < 4; ++i) {
          int row = wr * 64 + i * 16 + cl;
          a[i] = *(const half8*)(As + row * 64 + ((g ^ (row & 7)) << 3));
        }
#pragma unroll
        for (int j = 0; j < 4; ++j) {
          int n = wc * 64 + j * 16 + cl;
          b[j] = *(const half8*)(Bs + n * 64 + ((g ^ (n & 7)) << 3));
        }
#pragma unroll
        for (int i = 0; i < 4; ++i)
#pragma unroll
          for (int j = 0; j < 4; ++j)
            acc[i][j] = __builtin_amdgcn_mfma_f32_16x16x32_f16(a[i], b[j], acc[i][j], 0, 0, 0);
      }
    }
    if (isgw) {
#pragma unroll
      for (int i = 0; i < 4; ++i)
#pragma unroll
        for (int q = 0; q < 4; ++q) {
          int pr = rowbase + wr * 64 + i * 16 + kg * 4 + q;
#pragma unroll
          for (int j = 0; j < 4; ++j) {
            int pc = colbase + wc * 64 + j * 16 + cl;
            G[(size_t)r * 65536 + pr * 256 + pc] = f2h(acc[i][j][q]);
          }
        }
    } else {
      float s = 0.f;
#pragma unroll
      for (int i = 0; i < 4; ++i)
#pragma unroll
        for (int q = 0; q < 4; ++q) {
          int rg = rowbase + wr * 64 + i * 16 + kg * 4 + q;
#pragma unroll
          for (int j = 0; j < 4; ++j) {
            int cg = colbase + wc * 64 + j * 16 + cl;
            float dd = acc[i][j][q] - (rg == cg ? 1.0f : 0.0f);
            s += dd * dd;
          }
        }
#pragma unroll
      for (int d = 1; d < 64; d <<= 1) s += __shfl_xor(s, d);
      if (lane == 0) red4[w] = s;
      __syncthreads();
      if (tid == 0)
        pbw[bid - 256] = red4[0] + red4[1] + red4[2] + red4[3];
    }
  } else {
    int r = bid - 260;
    bvl[tid] = bv[r * 256 + tid];
    __syncthreads();
    float s = 0.f;
#pragma unroll 8
    for (int c8 = 0; c8 < 32; ++c8) {
      ushort8 wv8 = *(const ushort8*)(woh + tid * 256 + c8 * 8);
#pragma unroll
      for (int e = 0; e < 8; ++e) s = fmaf(h2f(wv8[e]), bvl[c8 * 8 + e], s);
    }
    hv[r * 256 + tid] = s;
  }
}

// ============ k_fire: tile 128bc x 256m, 4 waves of 64x128, BK=32 dbuf 2-phase ============
// grid 2048 linear (XCD-swizzled to (32bc, 64r)), 256 thr
__global__ __launch_bounds__(256, 2) void k_fire(
    const unsigned short* __restrict__ xh, const unsigned short* __restrict__ wd,
    const float* __restrict__ bdr, float* __restrict__ fire_p) {
  __shared__ unsigned short As[2][128 * 32];  // 2x8KB
  __shared__ unsigned short Bs[2][256 * 32];  // 2x16KB
  __shared__ float red[128][2];               // 1KB
  const int tid = threadIdx.x, w = tid >> 6, lane = tid & 63;
  const int wr = w >> 1, wc = w & 1, cl = lane & 15, kg = lane >> 4;
  const int wg = blockIdx.x;
  const int swz = (wg & 7) * 256 + (wg >> 3);
  const int bc0 = (swz & 31) * 128, r = swz >> 5;

  auto stage = [&](int t) {
    const int kc = t * 32;
    unsigned short* da = (unsigned short*)As[t & 1];
    unsigned short* db = (unsigned short*)Bs[t & 1];
#pragma unroll
    for (int j = 0; j < 2; ++j) {  // A: 128x32 = 8 slabs
      int s = w * 2 + j;
      int ch = s * 64 + lane;
      int row = ch >> 2, c = ch & 3;
      gload16(xh + (size_t)(bc0 + row) * 256 + kc + ((c ^ ((row >> 1) & 3)) << 3),
              da + s * 512);
    }
#pragma unroll
    for (int j = 0; j < 4; ++j) {  // B: 256x32 = 16 slabs
      int s = w * 4 + j;
      int ch = s * 64 + lane;
      int n = ch >> 2, c = ch & 3;
      gload16(wd + (size_t)r * 65536 + n * 256 + kc + ((c ^ ((n >> 1) & 3)) << 3),
              db + s * 512);
    }
  };

  float bdrv[8];
#pragma unroll
  for (int j = 0; j < 8; ++j)
    bdrv[j] = bdr[r * 256 + wc * 128 + j * 16 + cl];

  f32x4 acc[4][8];
#pragma unroll
  for (int i = 0; i < 4; ++i)
#pragma unroll
    for (int j = 0; j < 8; ++j) acc[i][j] = (f32x4){0.f, 0.f, 0.f, 0.f};

  stage(0);
  for (int t = 0; t < 8; ++t) {
    __syncthreads();               // drains stage(t) (vmcnt 0) + syncs waves
    if (t + 1 < 8) stage(t + 1);   // issue next stage; overlaps compute below
    const unsigned short* Ac = As[t & 1];
    const unsigned short* Bc = Bs[t & 1];
    half8 a[4], b[8];
#pragma unroll
    for (int i = 0; i < 4; ++i) {
      int row = wr * 64 + i * 16 + cl;
      a[i] = *(const half8*)(Ac + row * 32 + ((kg ^ ((row >> 1) & 3)) << 3));
    }
#pragma unroll
    for (int j = 0; j < 8; ++j) {
      int n = wc * 128 + j * 16 + cl;
      b[j] = *(const half8*)(Bc + n * 32 + ((kg ^ ((n >> 1) & 3)) << 3));
    }
#pragma unroll
    for (int i = 0; i < 4; ++i)
#pragma unroll
      for (int j = 0; j < 8; ++j)
        acc[i][j] = __builtin_amdgcn_mfma_f32_16x16x32_f16(a[i], b[j], acc[i][j], 0, 0, 0);
  }
  float rowsum[4][4];
#pragma unroll
  for (int i = 0; i < 4; ++i)
#pragma unroll
    for (int q = 0; q < 4; ++q) {
      float s2 = 0.f;
#pragma unroll
      for (int j = 0; j < 8; ++j) {
        float t2 = acc[i][j][q] + bdrv[j];
        s2 += t2 * t2;
      }
      rowsum[i][q] = s2;
    }
#pragma unroll
  for (int dlt = 1; dlt < 16; dlt <<= 1)
#pragma unroll
    for (int i = 0; i < 4; ++i)
#pragma unroll
      for (int q = 0; q < 4; ++q) rowsum[i][q] += __shfl_xor(rowsum[i][q], dlt);
  if (cl == 0) {
#pragma unroll
    for (int i = 0; i < 4; ++i)
#pragma unroll
      for (int q = 0; q < 4; ++q)
        red[wr * 64 + i * 16 + kg * 4 + q][wc] = rowsum[i][q];
  }
  __syncthreads();
  if (tid < 128)
    fire_p[(size_t)(bc0 + tid) * 64 + r] = red[tid][0] + red[tid][1];
}

// ---------------- mask: exp + top-p over 64 rules ----------------
__global__ __launch_bounds__(256) void k_mask(const float* __restrict__ fire_p,
                                              float* __restrict__ nfs, float tau) {
  int w = threadIdx.x >> 6, lane = threadIdx.x & 63;
  int bc = blockIdx.x * 4 + w;
  size_t ix = (size_t)bc * 64 + lane;
  float f = expf(-0.001953125f * fire_p[ix]) + EPS_F;
  float tot = f;
#pragma unroll
  for (int d = 1; d < 64; d <<= 1) tot += __shfl_xor(tot, d);
  float nf = f / (tot + EPS_F);
  float v = nf;
#pragma unroll
  for (int k = 2; k <= 64; k <<= 1) {
#pragma unroll
    for (int j = 32; j > 0; j >>= 1) {
      if (j >= k) continue;
      float o = __shfl_xor(v, j);
      bool lower = (lane & j) == 0;
      bool desc = (lane & k) == 0;
      float mn = fminf(v, o), mx = fmaxf(v, o);
      v = (desc == lower) ? mx : mn;
    }
  }
  float cs = v;
#pragma unroll
  for (int d = 1; d < 64; d <<= 1) {
    float t = __shfl_up(cs, d);
    if (lane >= d) cs += t;
  }
  float err = cs - tau;
  if (err < 0.f) err = 1.0f;
  float mn = err;
#pragma unroll
  for (int d = 1; d < 64; d <<= 1) mn = fminf(mn, __shfl_xor(mn, d));
  unsigned long long ball = __ballot(err == mn);
  int idx = __ffsll(ball) - 1;
  float thresh = __shfl(v, idx);
  float keep = (nf >= thresh) ? nf : 0.0f;
  float tot2 = keep;
#pragma unroll
  for (int d = 1; d < 64; d <<= 1) tot2 += __shfl_xor(tot2, d);
  nfs[ix] = keep / (tot2 + EPS_F);
}

// ============ k_predg: 512 thr (8 waves of 32bc x 64p'), BK=32 dbuf 2-phase ============
// grid 512 linear (XCD-swizzled, slice per XCD)
__global__ __launch_bounds__(512, 4) void k_predg(
    const unsigned short* __restrict__ xh, const unsigned short* __restrict__ G,
    const float* __restrict__ nfs, const float* __restrict__ hv,
    unsigned short* __restrict__ pp) {
  __shared__ unsigned short As[2][128 * 32];  // 2x8KB
  __shared__ unsigned short Bs[2][128 * 32];  // 2x8KB
  __shared__ float nl[128][9];                // 4.5KB padded
  const int tid = threadIdx.x, w = tid >> 6, lane = tid & 63;
  const int wr = w >> 1, wc = w & 1, cl = lane & 15, kg = lane >> 4;
  const int wg = blockIdx.x;
  const int swz = (wg & 7) * 64 + (wg >> 3);
  const int sl = swz >> 6, inner = swz & 63;
  const int bc0 = ((inner >> 1) & 31) * 128, ph = inner & 1;

  auto stage = [&](int t) {
    const int rr = t >> 3, kc = (t & 7) * 32;
    unsigned short* da = (unsigned short*)As[t & 1];
    unsigned short* db = (unsigned short*)Bs[t & 1];
    {  // A: 128x32 = 8 slabs, 1 per wave
      int s = w;
      int ch = s * 64 + lane;
      int row = ch >> 2, c = ch & 3;
      gload16(xh + (size_t)(bc0 + row) * 256 + kc + ((c ^ ((row >> 1) & 3)) << 3),
              da + s * 512);
    }
    {  // B: 128x32 = 8 slabs, 1 per wave
      int s = w;
      int ch = s * 64 + lane;
      int n = ch >> 2, c = ch & 3;
      gload16(G + (size_t)(sl * 8 + rr) * 65536 + (ph * 128 + n) * 256 + kc +
                  ((c ^ ((n >> 1) & 3)) << 3),
              db + s * 512);
    }
  };

  for (int e = tid; e < 1024; e += 512)
    nl[e >> 3][e & 7] = nfs[(size_t)(bc0 + (e >> 3)) * 64 + sl * 8 + (e & 7)];

  f32x4 acc[2][4];
#pragma unroll
  for (int i = 0; i < 2; ++i)
#pragma unroll
    for (int j = 0; j < 4; ++j) acc[i][j] = (f32x4){0.f, 0.f, 0.f, 0.f};

  stage(0);
  _Float16 nlh[2];
  for (int t = 0; t < 64; ++t) {
    const int rr = t >> 3;
    __syncthreads();                 // drains stage(t) + nl on t==0
    if (t + 1 < 64) stage(t + 1);    // overlaps compute below
    if ((t & 7) == 0) {
#pragma unroll
      for (int i = 0; i < 2; ++i)
        nlh[i] = (_Float16)nl[wr * 32 + i * 16 + cl][rr];
    }
    const unsigned short* Ac = As[t & 1];
    const unsigned short* Bc = Bs[t & 1];
    half8 a[2], b[4];
#pragma unroll
    for (int i = 0; i < 2; ++i) {
      int row = wr * 32 + i * 16 + cl;
      a[i] = *(const half8*)(Ac + row * 32 + ((kg ^ ((row >> 1) & 3)) << 3));
      a[i] = a[i] * nlh[i];
    }
#pragma unroll
    for (int j = 0; j < 4; ++j) {
      int n = wc * 64 + j * 16 + cl;
      b[j] = *(const half8*)(Bc + n * 32 + ((kg ^ ((n >> 1) & 3)) << 3));
    }
#pragma unroll
    for (int i = 0; i < 2; ++i)
#pragma unroll
      for (int j = 0; j < 4; ++j)
        acc[i][j] = __builtin_amdgcn_mfma_f32_16x16x32_f16(a[i], b[j], acc[i][j], 0, 0, 0);
  }
  float hvv[8][4];
#pragma unroll
  for (int j = 0; j < 4; ++j) {
    int col = ph * 128 + wc * 64 + j * 16 + cl;
#pragma unroll
    for (int rr = 0; rr < 8; ++rr)
      hvv[rr][j] = hv[(sl * 8 + rr) * 256 + col];
  }
  unsigned short* base = pp + (size_t)sl * 1048576;
#pragma unroll
  for (int i = 0; i < 2; ++i)
#pragma unroll
    for (int q = 0; q < 4; ++q) {
      int outrow = wr * 32 + i * 16 + kg * 4 + q;
      float nlv[8];
#pragma unroll
      for (int rr = 0; rr < 8; ++rr) nlv[rr] = nl[outrow][rr];
#pragma unroll
      for (int j = 0; j < 4; ++j) {
        float s = acc[i][j][q];
#pragma unroll
        for (int rr = 0; rr < 8; ++rr) s = fmaf(nlv[rr], hvv[rr][j], s);
        int col = ph * 128 + wc * 64 + j * 16 + cl;
        base[(size_t)(bc0 + outrow) * 256 + col] = f2h(s);
      }
    }
}

// ---------------- finalize output: out[b][p][c] = sum_s pp_s + bo (LDS transpose) ----------------
__global__ __launch_bounds__(256) void k_finalout(const unsigned short* __restrict__ pp,
                                                  const float* __restrict__ bo,
                                                  float* __restrict__ out) {
  __shared__ float sacc[256][33];
  __shared__ float bol[256];
  const int tid = threadIdx.x;
  bol[tid] = bo[tid];
  const int bc0 = blockIdx.x * 32;
  const int b = bc0 >> 9, c0 = bc0 & 511;
#pragma unroll
  for (int i = 0; i < 4; ++i) {
    int unit = tid + 256 * i;
    int pch = unit & 31, lbc = unit >> 5;
    float s[8];
#pragma unroll
    for (int e = 0; e < 8; ++e) s[e] = 0.f;
#pragma unroll
    for (int sl = 0; sl < 8; ++sl) {
      ushort8 v = *(const ushort8*)(pp + (size_t)sl * 1048576 +
                                    (size_t)(bc0 + lbc) * 256 + pch * 8);
#pragma unroll
      for (int e = 0; e < 8; ++e) s[e] += h2f(v[e]);
    }
#pragma unroll
    for (int e = 0; e < 8; ++e) sacc[pch * 8 + e][lbc] = s[e];
  }
  __syncthreads();
  const int p = tid;
  float bov = bol[p];
  float* dst = out + (size_t)b * 131072 + (size_t)p * 512 + c0;
#pragma unroll
  for (int e0 = 0; e0 < 8; ++e0) {
    float4 v;
    v.x = sacc[p][e0 * 4 + 0] + bov;
    v.y = sacc[p][e0 * 4 + 1] + bov;
    v.z = sacc[p][e0 * 4 + 2] + bov;
    v.w = sacc[p][e0 * 4 + 3] + bov;
    *(float4*)(dst + e0 * 4) = v;
  }
}

// ---------------- finalize loss (1024 thr) ----------------
__global__ __launch_bounds__(1024) void k_final(
    const float* __restrict__ bq, const float* __restrict__ bk,
    const float* __restrict__ bv, const float* __restrict__ bo,
    const float* __restrict__ pbw, const float* __restrict__ pbk,
    const float* __restrict__ pbv, float* __restrict__ loss_out) {
  __shared__ float r[16][5];
  const int tid = threadIdx.x;
  float swq = (tid < 4) ? pbw[tid] : 0.f;
  float sbk = 0.f, sbv = 0.f;
  for (int i = tid; i < 4096; i += 1024) {
    sbk += pbk[i];
    sbv += pbv[i];
  }
  for (int i = tid; i < 16384; i += 1024) {
    sbk += fabsf(bk[i]);
    sbv += fabsf(bv[i]);
  }
  float sbq = 0.f, sbo = 0.f;
  if (tid < 256) {
    float a = bq[tid];
    sbq = a * a;
    float b = bo[tid];
    sbo = b * b;
  }
  int lane = tid & 63, w = tid >> 6;
#pragma unroll
  for (int d = 1; d < 64; d <<= 1) {
    swq += __shfl_xor(swq, d);
    sbk += __shfl_xor(sbk, d);
    sbv += __shfl_xor(sbv, d);
    sbq += __shfl_xor(sbq, d);
    sbo += __shfl_xor(sbo, d);
  }
  if (lane == 0) {
    r[w][0] = swq; r[w][1] = sbk; r[w][2] = sbv; r[w][3] = sbq; r[w][4] = sbo;
  }
  __syncthreads();
  if (tid == 0) {
    float t[5] = {0.f, 0.f, 0.f, 0.f, 0.f};
    for (int i = 0; i < 16; ++i)
      for (int j = 0; j < 5; ++j) t[j] += r[i][j];
    float loss = 0.01f * (sqrtf(t[0]) + sqrtf(t[3]) + sqrtf(t[4])) +
                 0.001f * (t[1] + t[2]);
    *loss_out = loss;
  }
}

extern "C" void kernel_launch(void* const* d_in, const int* in_sizes, int n_in,
                              void* d_out, int out_size, void* d_ws, size_t ws_size,
                              hipStream_t stream) {
  const float* in    = (const float*)d_in[0];
  const float* Wq    = (const float*)d_in[1];
  const float* bq    = (const float*)d_in[2];
  const float* Wk    = (const float*)d_in[3];
  const float* bk    = (const float*)d_in[4];
  const float* Wv    = (const float*)d_in[5];
  const float* bv    = (const float*)d_in[6];
  const float* Wo    = (const float*)d_in[7];
  const float* bo    = (const float*)d_in[8];
  const float* sigma = (const float*)d_in[9];
  float* out = (float*)d_out;

  char* ws = (char*)d_ws;
  unsigned short* xh     = (unsigned short*)(ws);               // 2MB
  unsigned short* woh    = (unsigned short*)(ws + 2097152);     // 128KB
  float*          bdr    = (float*)(ws + 2228224);              // 64KB
  float*          nfs    = (float*)(ws + 2293760);              // 1MB
  float*          fire_p = (float*)(ws + 3342336);              // 1MB
  float*          pbk    = (float*)(ws + 4390912);              // 16KB
  float*          pbv    = (float*)(ws + 4407296);              // 16KB
  float*          pbw    = (float*)(ws + 4423680);              // 1KB
  float*          hv     = (float*)(ws + 4424704);              // 64KB
  unsigned short* wd     = (unsigned short*)(ws + 4718592);     // 8MB (dead after fire)
  unsigned short* wvT    = (unsigned short*)(ws + 13107200);    // 8MB (dead after gwx)
  unsigned short* pp     = (unsigned short*)(ws + 4718592);     // 8MB overlay (on wd)
  unsigned short* G      = (unsigned short*)(ws + 21495808);    // 8MB
  unsigned short* wqh    = (unsigned short*)(ws + 29884416);    // 128KB
  unsigned short* woT    = (unsigned short*)(ws + 30015488);    // 128KB

  k_prep_x<<<dim3(16, 8, 8), 256, 0, stream>>>(in, xh);
  k_prepwt<<<8256, 256, 0, stream>>>(Wq, Wk, Wv, Wo, bq, bk, sigma,
                                     wd, woh, wqh, bdr, pbk, wvT, woT, pbv);
  k_gwx<<<324, 256, 0, stream>>>(woh, wvT, wqh, woT, bv, G, pbw, hv);
  k_fire<<<2048, 256, 0, stream>>>(xh, wd, bdr, fire_p);
  const float tau = (float)(0.9 * pow(1.0 / (64.0 + (double)EPS_F), 1.0 / 256.0));
  k_mask<<<1024, 256, 0, stream>>>(fire_p, nfs, tau);
  k_predg<<<512, 512, 0, stream>>>(xh, G, nfs, hv, pp);
  k_finalout<<<128, 256, 0, stream>>>(pp, bo, out);
  k_final<<<1, 1024, 0, stream>>>(bq, bk, bv, bo, pbw, pbk, pbv, out + 1048576);
}

// Round 18
// 129.070 us; speedup vs baseline: 1.0602x; 1.0602x over previous
//
#include <hip/hip_runtime.h>
#include <math.h>

#define EPS_F 1.1754943508222875e-38f

typedef __attribute__((ext_vector_type(8))) _Float16 half8;
typedef __attribute__((ext_vector_type(4))) float f32x4;
typedef __attribute__((ext_vector_type(8))) unsigned short ushort8;

__device__ __forceinline__ unsigned short f2h(float f) {
  _Float16 h = (_Float16)f;
  return __builtin_bit_cast(unsigned short, h);
}
__device__ __forceinline__ float h2f(unsigned short u) {
  return (float)__builtin_bit_cast(_Float16, u);
}

// async global->LDS, 16B/lane; LDS dest = wave-uniform base (+ lane*16 by HW)
__device__ __forceinline__ void gload16(const void* g, void* l) {
  __builtin_amdgcn_global_load_lds(
      (const __attribute__((address_space(1))) void*)g,
      (__attribute__((address_space(3))) void*)l, 16, 0, 0);
}

// ---------------- prep: x transpose + f16 convert ----------------
__global__ __launch_bounds__(256) void k_prep_x(const float* __restrict__ in,
                                                unsigned short* __restrict__ x) {
  __shared__ float t[32][33];
  int c0 = blockIdx.x * 32, p0 = blockIdx.y * 32, b = blockIdx.z;
  int tx = threadIdx.x & 31, ty = threadIdx.x >> 5;
#pragma unroll
  for (int i = ty; i < 32; i += 8)
    t[i][tx] = in[(b * 256 + p0 + i) * 512 + c0 + tx];
  __syncthreads();
#pragma unroll
  for (int i = ty; i < 32; i += 8)
    x[(b * 512 + c0 + i) * 256 + p0 + tx] = f2h(t[tx][i]);
}

// ======== fused prep: bid<4096 -> prep_w; else -> transposes (wvT / woT) ========
__global__ __launch_bounds__(256) void k_prepwt(
    const float* __restrict__ Wq, const float* __restrict__ Wk,
    const float* __restrict__ Wv, const float* __restrict__ Wo,
    const float* __restrict__ bq, const float* __restrict__ bk,
    const float* __restrict__ sigma,
    unsigned short* __restrict__ wd, unsigned short* __restrict__ woh,
    unsigned short* __restrict__ wqh, float* __restrict__ bdr,
    float* __restrict__ pbk, unsigned short* __restrict__ wvT,
    unsigned short* __restrict__ woT, float* __restrict__ pbv) {
  __shared__ float t[32][33];
  __shared__ float r1[4];
  const int bid = blockIdx.x;
  const int lane = threadIdx.x & 63, w = threadIdx.x >> 6;
  if (bid < 4096) {
    int gid = bid * 256 + threadIdx.x;
    int i4 = gid * 4;
    int rm = i4 >> 8, p = i4 & 255, m = rm & 255;
    const float4 wk = *(const float4*)(Wk + i4);
    const float4 wq = *(const float4*)(Wq + m * 256 + p);
    float rs = 1.0f / (sigma[rm] + EPS_F);
    ushort4 d;
    d.x = f2h((wq.x - wk.x) * rs); d.y = f2h((wq.y - wk.y) * rs);
    d.z = f2h((wq.z - wk.z) * rs); d.w = f2h((wq.w - wk.w) * rs);
    *(ushort4*)(wd + i4) = d;
    float ak = fabsf(wk.x) + fabsf(wk.y) + fabsf(wk.z) + fabsf(wk.w);
    if (p == 0) bdr[rm] = (bq[m] - bk[rm]) * rs;
    if (gid < 65536) {
      woh[gid] = f2h(Wo[gid]);
      ushort4 q4;
      q4.x = f2h(wq.x); q4.y = f2h(wq.y); q4.z = f2h(wq.z); q4.w = f2h(wq.w);
      *(ushort4*)(wqh + i4) = q4;
    }
#pragma unroll
    for (int dlt = 1; dlt < 64; dlt <<= 1) ak += __shfl_xor(ak, dlt);
    if (lane == 0) r1[w] = ak;
    __syncthreads();
    if (threadIdx.x == 0)
      pbk[bid] = r1[0] + r1[1] + r1[2] + r1[3];
  } else {
    int tt = bid - 4096;
    int z = tt >> 6, rem = tt & 63;
    int bx = rem & 7, by = rem >> 3;
    int tx = threadIdx.x & 31, ty = threadIdx.x >> 5;
    if (z < 64) {
      int p0 = bx * 32, m0 = by * 32, r = z;
      float av = 0.f;
#pragma unroll
      for (int i = ty; i < 32; i += 8) {
        float v = Wv[(size_t)(r * 256 + m0 + i) * 256 + p0 + tx];
        t[i][tx] = v;
        av += fabsf(v);
      }
      __syncthreads();
#pragma unroll
      for (int i = ty; i < 32; i += 8)
        wvT[(size_t)r * 65536 + (p0 + i) * 256 + m0 + tx] = f2h(t[tx][i]);
#pragma unroll
      for (int d = 1; d < 64; d <<= 1) av += __shfl_xor(av, d);
      if (lane == 0) r1[w] = av;
      __syncthreads();
      if (threadIdx.x == 0)
        pbv[r * 64 + by * 8 + bx] = r1[0] + r1[1] + r1[2] + r1[3];
    } else {
      int p0 = bx * 32, m0 = by * 32;
#pragma unroll
      for (int i = ty; i < 32; i += 8)
        t[i][tx] = Wo[(p0 + i) * 256 + m0 + tx];
      __syncthreads();
#pragma unroll
      for (int i = ty; i < 32; i += 8)
        woT[(m0 + i) * 256 + p0 + tx] = f2h(t[tx][i]);
    }
  }
}

// ======== fused weight-GEMMs: bid<256 -> gw; 256..259 -> wqwo; 260..323 -> hv ========
__global__ __launch_bounds__(256) void k_gwx(
    const unsigned short* __restrict__ woh, const unsigned short* __restrict__ wvT,
    const unsigned short* __restrict__ wqh, const unsigned short* __restrict__ woT,
    const float* __restrict__ bv,
    unsigned short* __restrict__ G, float* __restrict__ pbw,
    float* __restrict__ hv) {
  __shared__ unsigned short As[128 * 64];
  __shared__ unsigned short Bs[128 * 64];
  __shared__ float red4[4];
  __shared__ float bvl[256];
  const int bid = blockIdx.x;
  const int tid = threadIdx.x, w = tid >> 6, lane = tid & 63;
  const int wr = w >> 1, wc = w & 1, cl = lane & 15, kg = lane >> 4;

  if (bid < 260) {
    const bool isgw = bid < 256;
    const int r = bid >> 2;
    const int rowbase = isgw ? (((bid >> 1) & 1) * 128) : (((bid - 256) >> 1) * 128);
    const int colbase = isgw ? ((bid & 1) * 128) : (((bid - 256) & 1) * 128);
    const unsigned short* Aglob = isgw ? woh : wqh;
    const unsigned short* Bglob = isgw ? (wvT + (size_t)r * 65536) : woT;

    f32x4 acc[4][4];
#pragma unroll
    for (int i = 0; i < 4; ++i)
#pragma unroll
      for (int j = 0; j < 4; ++j) acc[i][j] = (f32x4){0.f, 0.f, 0.f, 0.f};

    for (int tks = 0; tks < 4; ++tks) {
      const int kc = tks * 64;
      __syncthreads();
#pragma unroll
      for (int j = 0; j < 4; ++j) {
        int s = w * 4 + j;
        int ch = s * 64 + lane;
        int row = ch >> 3, c = ch & 7;
        gload16(Aglob + (rowbase + row) * 256 + kc + ((c ^ (row & 7)) << 3),
                As + s * 512);
        gload16(Bglob + (colbase + row) * 256 + kc + ((c ^ (row & 7)) << 3),
                Bs + s * 512);
      }
      __syncthreads();
#pragma unroll
      for (int kk = 0; kk < 2; ++kk) {
        half8 a[4], b[4];
        int g = kk * 4 + kg;
#pragma unroll
        for (int i = 0; i < 4; ++i) {
          int row = wr * 64 + i * 16 + cl;
          a[i] = *(const half8*)(As + row * 64 + ((g ^ (row & 7)) << 3));
        }
#pragma unroll
        for (int j = 0; j < 4; ++j) {
          int n = wc * 64 + j * 16 + cl;
          b[j] = *(const half8*)(Bs + n * 64 + ((g ^ (n & 7)) << 3));
        }
#pragma unroll
        for (int i = 0; i < 4; ++i)
#pragma unroll
          for (int j = 0; j < 4; ++j)
            acc[i][j] = __builtin_amdgcn_mfma_f32_16x16x32_f16(a[i], b[j], acc[i][j], 0, 0, 0);
      }
    }
    if (isgw) {
#pragma unroll
      for (int i = 0; i < 4; ++i)
#pragma unroll
        for (int q = 0; q < 4; ++q) {
          int pr = rowbase + wr * 64 + i * 16 + kg * 4 + q;
#pragma unroll
          for (int j = 0; j < 4; ++j) {
            int pc = colbase + wc * 64 + j * 16 + cl;
            G[(size_t)r * 65536 + pr * 256 + pc] = f2h(acc[i][j][q]);
          }
        }
    } else {
      float s = 0.f;
#pragma unroll
      for (int i = 0; i < 4; ++i)
#pragma unroll
        for (int q = 0; q < 4; ++q) {
          int rg = rowbase + wr * 64 + i * 16 + kg * 4 + q;
#pragma unroll
          for (int j = 0; j < 4; ++j) {
            int cg = colbase + wc * 64 + j * 16 + cl;
            float dd = acc[i][j][q] - (rg == cg ? 1.0f : 0.0f);
            s += dd * dd;
          }
        }
#pragma unroll
      for (int d = 1; d < 64; d <<= 1) s += __shfl_xor(s, d);
      if (lane == 0) red4[w] = s;
      __syncthreads();
      if (tid == 0)
        pbw[bid - 256] = red4[0] + red4[1] + red4[2] + red4[3];
    }
  } else {
    int r = bid - 260;
    bvl[tid] = bv[r * 256 + tid];
    __syncthreads();
    float s = 0.f;
#pragma unroll 8
    for (int c8 = 0; c8 < 32; ++c8) {
      ushort8 wv8 = *(const ushort8*)(woh + tid * 256 + c8 * 8);
#pragma unroll
      for (int e = 0; e < 8; ++e) s = fmaf(h2f(wv8[e]), bvl[c8 * 8 + e], s);
    }
    hv[r * 256 + tid] = s;
  }
}

// ============ k_fire: tile 128bc x 256m, 4 waves of 64x128, BK=64, 2-sync ============
// grid 2048 linear (XCD-swizzled to (32bc, 64r)), 256 thr
__global__ __launch_bounds__(256, 2) void k_fire(
    const unsigned short* __restrict__ xh, const unsigned short* __restrict__ wd,
    const float* __restrict__ bdr, float* __restrict__ fire_p) {
  __shared__ unsigned short As[128 * 64];  // 16KB
  __shared__ unsigned short Bs[256 * 64];  // 32KB
  __shared__ float red[128][2];            // 1KB
  const int tid = threadIdx.x, w = tid >> 6, lane = tid & 63;
  const int wr = w >> 1, wc = w & 1, cl = lane & 15, kg = lane >> 4;
  const int wg = blockIdx.x;
  const int swz = (wg & 7) * 256 + (wg >> 3);
  const int bc0 = (swz & 31) * 128, r = swz >> 5;

  float bdrv[8];
#pragma unroll
  for (int j = 0; j < 8; ++j)
    bdrv[j] = bdr[r * 256 + wc * 128 + j * 16 + cl];

  f32x4 acc[4][8];
#pragma unroll
  for (int i = 0; i < 4; ++i)
#pragma unroll
    for (int j = 0; j < 8; ++j) acc[i][j] = (f32x4){0.f, 0.f, 0.f, 0.f};

  for (int t = 0; t < 4; ++t) {
    const int kc = t * 64;
    __syncthreads();
#pragma unroll
    for (int j = 0; j < 4; ++j) {  // A: 128x64 = 16 slabs
      int s = w * 4 + j;
      int ch = s * 64 + lane;
      int row = ch >> 3, c = ch & 7;
      gload16(xh + (size_t)(bc0 + row) * 256 + kc + ((c ^ (row & 7)) << 3),
              As + s * 512);
    }
#pragma unroll
    for (int j = 0; j < 8; ++j) {  // B: 256x64 = 32 slabs
      int s = w * 8 + j;
      int ch = s * 64 + lane;
      int n = ch >> 3, c = ch & 7;
      gload16(wd + (size_t)r * 65536 + n * 256 + kc + ((c ^ (n & 7)) << 3),
              Bs + s * 512);
    }
    __syncthreads();
#pragma unroll
    for (int kk = 0; kk < 2; ++kk) {
      half8 a[4], b[8];
      int g = kk * 4 + kg;
#pragma unroll
      for (int i = 0; i < 4; ++i) {
        int row = wr * 64 + i * 16 + cl;
        a[i] = *(const half8*)(As + row * 64 + ((g ^ (row & 7)) << 3));
      }
#pragma unroll
      for (int j = 0; j < 8; ++j) {
        int n = wc * 128 + j * 16 + cl;
        b[j] = *(const half8*)(Bs + n * 64 + ((g ^ (n & 7)) << 3));
      }
#pragma unroll
      for (int i = 0; i < 4; ++i)
#pragma unroll
        for (int j = 0; j < 8; ++j)
          acc[i][j] = __builtin_amdgcn_mfma_f32_16x16x32_f16(a[i], b[j], acc[i][j], 0, 0, 0);
    }
  }
  float rowsum[4][4];
#pragma unroll
  for (int i = 0; i < 4; ++i)
#pragma unroll
    for (int q = 0; q < 4; ++q) {
      float s2 = 0.f;
#pragma unroll
      for (int j = 0; j < 8; ++j) {
        float t2 = acc[i][j][q] + bdrv[j];
        s2 += t2 * t2;
      }
      rowsum[i][q] = s2;
    }
#pragma unroll
  for (int dlt = 1; dlt < 16; dlt <<= 1)
#pragma unroll
    for (int i = 0; i < 4; ++i)
#pragma unroll
      for (int q = 0; q < 4; ++q) rowsum[i][q] += __shfl_xor(rowsum[i][q], dlt);
  if (cl == 0) {
#pragma unroll
    for (int i = 0; i < 4; ++i)
#pragma unroll
      for (int q = 0; q < 4; ++q)
        red[wr * 64 + i * 16 + kg * 4 + q][wc] = rowsum[i][q];
  }
  __syncthreads();
  if (tid < 128)
    fire_p[(size_t)(bc0 + tid) * 64 + r] = red[tid][0] + red[tid][1];
}

// ---------------- mask: exp + top-p over 64 rules ----------------
__global__ __launch_bounds__(256) void k_mask(const float* __restrict__ fire_p,
                                              float* __restrict__ nfs, float tau) {
  int w = threadIdx.x >> 6, lane = threadIdx.x & 63;
  int bc = blockIdx.x * 4 + w;
  size_t ix = (size_t)bc * 64 + lane;
  float f = expf(-0.001953125f * fire_p[ix]) + EPS_F;
  float tot = f;
#pragma unroll
  for (int d = 1; d < 64; d <<= 1) tot += __shfl_xor(tot, d);
  float nf = f / (tot + EPS_F);
  float v = nf;
#pragma unroll
  for (int k = 2; k <= 64; k <<= 1) {
#pragma unroll
    for (int j = 32; j > 0; j >>= 1) {
      if (j >= k) continue;
      float o = __shfl_xor(v, j);
      bool lower = (lane & j) == 0;
      bool desc = (lane & k) == 0;
      float mn = fminf(v, o), mx = fmaxf(v, o);
      v = (desc == lower) ? mx : mn;
    }
  }
  float cs = v;
#pragma unroll
  for (int d = 1; d < 64; d <<= 1) {
    float t = __shfl_up(cs, d);
    if (lane >= d) cs += t;
  }
  float err = cs - tau;
  if (err < 0.f) err = 1.0f;
  float mn = err;
#pragma unroll
  for (int d = 1; d < 64; d <<= 1) mn = fminf(mn, __shfl_xor(mn, d));
  unsigned long long ball = __ballot(err == mn);
  int idx = __ffsll(ball) - 1;
  float thresh = __shfl(v, idx);
  float keep = (nf >= thresh) ? nf : 0.0f;
  float tot2 = keep;
#pragma unroll
  for (int d = 1; d < 64; d <<= 1) tot2 += __shfl_xor(tot2, d);
  nfs[ix] = keep / (tot2 + EPS_F);
}

// ============ k_predg: 512 thr (8 waves of 32bc x 64p'), BK=64, 2-sync ============
// grid 512 linear (XCD-swizzled, slice per XCD)
__global__ __launch_bounds__(512, 4) void k_predg(
    const unsigned short* __restrict__ xh, const unsigned short* __restrict__ G,
    const float* __restrict__ nfs, const float* __restrict__ hv,
    unsigned short* __restrict__ pp) {
  __shared__ unsigned short As[128 * 64];  // 16KB
  __shared__ unsigned short Bs[128 * 64];  // 16KB
  __shared__ float nl[128][9];             // 4.5KB padded
  const int tid = threadIdx.x, w = tid >> 6, lane = tid & 63;
  const int wr = w >> 1, wc = w & 1, cl = lane & 15, kg = lane >> 4;
  const int wg = blockIdx.x;
  const int swz = (wg & 7) * 64 + (wg >> 3);  // XCD k <-> slice k
  const int sl = swz >> 6, inner = swz & 63;
  const int bc0 = ((inner >> 1) & 31) * 128, ph = inner & 1;

  for (int e = tid; e < 1024; e += 512)
    nl[e >> 3][e & 7] = nfs[(size_t)(bc0 + (e >> 3)) * 64 + sl * 8 + (e & 7)];

  f32x4 acc[2][4];
#pragma unroll
  for (int i = 0; i < 2; ++i)
#pragma unroll
    for (int j = 0; j < 4; ++j) acc[i][j] = (f32x4){0.f, 0.f, 0.f, 0.f};

  _Float16 nlh[2];
  for (int t = 0; t < 32; ++t) {
    const int rr = t >> 2, kc = (t & 3) * 64;
    __syncthreads();
#pragma unroll
    for (int j = 0; j < 2; ++j) {
      int s = w * 2 + j;
      int ch = s * 64 + lane;
      int row = ch >> 3, c = ch & 7;
      gload16(xh + (size_t)(bc0 + row) * 256 + kc + ((c ^ (row & 7)) << 3),
              As + s * 512);
      gload16(G + (size_t)(sl * 8 + rr) * 65536 + (ph * 128 + row) * 256 + kc +
                  ((c ^ (row & 7)) << 3),
              Bs + s * 512);
    }
    __syncthreads();
    if ((t & 3) == 0) {
#pragma unroll
      for (int i = 0; i < 2; ++i)
        nlh[i] = (_Float16)nl[wr * 32 + i * 16 + cl][rr];
    }
#pragma unroll
    for (int kk = 0; kk < 2; ++kk) {
      half8 a[2], b[4];
      int g = kk * 4 + kg;
#pragma unroll
      for (int i = 0; i < 2; ++i) {
        int row = wr * 32 + i * 16 + cl;
        a[i] = *(const half8*)(As + row * 64 + ((g ^ (row & 7)) << 3));
        a[i] = a[i] * nlh[i];
      }
#pragma unroll
      for (int j = 0; j < 4; ++j) {
        int n = wc * 64 + j * 16 + cl;
        b[j] = *(const half8*)(Bs + n * 64 + ((g ^ (n & 7)) << 3));
      }
#pragma unroll
      for (int i = 0; i < 2; ++i)
#pragma unroll
        for (int j = 0; j < 4; ++j)
          acc[i][j] = __builtin_amdgcn_mfma_f32_16x16x32_f16(a[i], b[j], acc[i][j], 0, 0, 0);
    }
  }
  float hvv[8][4];
#pragma unroll
  for (int j = 0; j < 4; ++j) {
    int col = ph * 128 + wc * 64 + j * 16 + cl;
#pragma unroll
    for (int rr = 0; rr < 8; ++rr)
      hvv[rr][j] = hv[(sl * 8 + rr) * 256 + col];
  }
  unsigned short* base = pp + (size_t)sl * 1048576;
#pragma unroll
  for (int i = 0; i < 2; ++i)
#pragma unroll
    for (int q = 0; q < 4; ++q) {
      int outrow = wr * 32 + i * 16 + kg * 4 + q;
      float nlv[8];
#pragma unroll
      for (int rr = 0; rr < 8; ++rr) nlv[rr] = nl[outrow][rr];
#pragma unroll
      for (int j = 0; j < 4; ++j) {
        float s = acc[i][j][q];
#pragma unroll
        for (int rr = 0; rr < 8; ++rr) s = fmaf(nlv[rr], hvv[rr][j], s);
        int col = ph * 128 + wc * 64 + j * 16 + cl;
        base[(size_t)(bc0 + outrow) * 256 + col] = f2h(s);
      }
    }
}

// ---------------- finalize output: out[b][p][c] = sum_s pp_s + bo (LDS transpose) ----------------
__global__ __launch_bounds__(256) void k_finalout(const unsigned short* __restrict__ pp,
                                                  const float* __restrict__ bo,
                                                  float* __restrict__ out) {
  __shared__ float sacc[256][33];
  __shared__ float bol[256];
  const int tid = threadIdx.x;
  bol[tid] = bo[tid];
  const int bc0 = blockIdx.x * 32;
  const int b = bc0 >> 9, c0 = bc0 & 511;
#pragma unroll
  for (int i = 0; i < 4; ++i) {
    int unit = tid + 256 * i;
    int pch = unit & 31, lbc = unit >> 5;
    float s[8];
#pragma unroll
    for (int e = 0; e < 8; ++e) s[e] = 0.f;
#pragma unroll
    for (int sl = 0; sl < 8; ++sl) {
      ushort8 v = *(const ushort8*)(pp + (size_t)sl * 1048576 +
                                    (size_t)(bc0 + lbc) * 256 + pch * 8);
#pragma unroll
      for (int e = 0; e < 8; ++e) s[e] += h2f(v[e]);
    }
#pragma unroll
    for (int e = 0; e < 8; ++e) sacc[pch * 8 + e][lbc] = s[e];
  }
  __syncthreads();
  const int p = tid;
  float bov = bol[p];
  float* dst = out + (size_t)b * 131072 + (size_t)p * 512 + c0;
#pragma unroll
  for (int e0 = 0; e0 < 8; ++e0) {
    float4 v;
    v.x = sacc[p][e0 * 4 + 0] + bov;
    v.y = sacc[p][e0 * 4 + 1] + bov;
    v.z = sacc[p][e0 * 4 + 2] + bov;
    v.w = sacc[p][e0 * 4 + 3] + bov;
    *(float4*)(dst + e0 * 4) = v;
  }
}

// ---------------- finalize loss (1024 thr) ----------------
__global__ __launch_bounds__(1024) void k_final(
    const float* __restrict__ bq, const float* __restrict__ bk,
    const float* __restrict__ bv, const float* __restrict__ bo,
    const float* __restrict__ pbw, const float* __restrict__ pbk,
    const float* __restrict__ pbv, float* __restrict__ loss_out) {
  __shared__ float r[16][5];
  const int tid = threadIdx.x;
  float swq = (tid < 4) ? pbw[tid] : 0.f;
  float sbk = 0.f, sbv = 0.f;
  for (int i = tid; i < 4096; i += 1024) {
    sbk += pbk[i];
    sbv += pbv[i];
  }
  for (int i = tid; i < 16384; i += 1024) {
    sbk += fabsf(bk[i]);
    sbv += fabsf(bv[i]);
  }
  float sbq = 0.f, sbo = 0.f;
  if (tid < 256) {
    float a = bq[tid];
    sbq = a * a;
    float b = bo[tid];
    sbo = b * b;
  }
  int lane = tid & 63, w = tid >> 6;
#pragma unroll
  for (int d = 1; d < 64; d <<= 1) {
    swq += __shfl_xor(swq, d);
    sbk += __shfl_xor(sbk, d);
    sbv += __shfl_xor(sbv, d);
    sbq += __shfl_xor(sbq, d);
    sbo += __shfl_xor(sbo, d);
  }
  if (lane == 0) {
    r[w][0] = swq; r[w][1] = sbk; r[w][2] = sbv; r[w][3] = sbq; r[w][4] = sbo;
  }
  __syncthreads();
  if (tid == 0) {
    float t[5] = {0.f, 0.f, 0.f, 0.f, 0.f};
    for (int i = 0; i < 16; ++i)
      for (int j = 0; j < 5; ++j) t[j] += r[i][j];
    float loss = 0.01f * (sqrtf(t[0]) + sqrtf(t[3]) + sqrtf(t[4])) +
                 0.001f * (t[1] + t[2]);
    *loss_out = loss;
  }
}

extern "C" void kernel_launch(void* const* d_in, const int* in_sizes, int n_in,
                              void* d_out, int out_size, void* d_ws, size_t ws_size,
                              hipStream_t stream) {
  const float* in    = (const float*)d_in[0];
  const float* Wq    = (const float*)d_in[1];
  const float* bq    = (const float*)d_in[2];
  const float* Wk    = (const float*)d_in[3];
  const float* bk    = (const float*)d_in[4];
  const float* Wv    = (const float*)d_in[5];
  const float* bv    = (const float*)d_in[6];
  const float* Wo    = (const float*)d_in[7];
  const float* bo    = (const float*)d_in[8];
  const float* sigma = (const float*)d_in[9];
  float* out = (float*)d_out;

  char* ws = (char*)d_ws;
  unsigned short* xh     = (unsigned short*)(ws);               // 2MB
  unsigned short* woh    = (unsigned short*)(ws + 2097152);     // 128KB
  float*          bdr    = (float*)(ws + 2228224);              // 64KB
  float*          nfs    = (float*)(ws + 2293760);              // 1MB
  float*          fire_p = (float*)(ws + 3342336);              // 1MB
  float*          pbk    = (float*)(ws + 4390912);              // 16KB
  float*          pbv    = (float*)(ws + 4407296);              // 16KB
  float*          pbw    = (float*)(ws + 4423680);              // 1KB
  float*          hv     = (float*)(ws + 4424704);              // 64KB
  unsigned short* wd     = (unsigned short*)(ws + 4718592);     // 8MB (dead after fire)
  unsigned short* wvT    = (unsigned short*)(ws + 13107200);    // 8MB (dead after gwx)
  unsigned short* pp     = (unsigned short*)(ws + 4718592);     // 8MB overlay (on wd)
  unsigned short* G      = (unsigned short*)(ws + 21495808);    // 8MB
  unsigned short* wqh    = (unsigned short*)(ws + 29884416);    // 128KB
  unsigned short* woT    = (unsigned short*)(ws + 30015488);    // 128KB

  k_prep_x<<<dim3(16, 8, 8), 256, 0, stream>>>(in, xh);
  k_prepwt<<<8256, 256, 0, stream>>>(Wq, Wk, Wv, Wo, bq, bk, sigma,
                                     wd, woh, wqh, bdr, pbk, wvT, woT, pbv);
  k_gwx<<<324, 256, 0, stream>>>(woh, wvT, wqh, woT, bv, G, pbw, hv);
  k_fire<<<2048, 256, 0, stream>>>(xh, wd, bdr, fire_p);
  const float tau = (float)(0.9 * pow(1.0 / (64.0 + (double)EPS_F), 1.0 / 256.0));
  k_mask<<<1024, 256, 0, stream>>>(fire_p, nfs, tau);
  k_predg<<<512, 512, 0, stream>>>(xh, G, nfs, hv, pp);
  k_finalout<<<128, 256, 0, stream>>>(pp, bo, out);
  k_final<<<1, 1024, 0, stream>>>(bq, bk, bv, bo, pbw, pbk, pbv, out + 1048576);
}